// Round 4
// baseline (405.886 us; speedup 1.0000x reference)
//
#include <hip/hip_runtime.h>

// GCN fused, fp16 MFMA. B=16384 graphs, N=16 nodes, 256->128->64->32, node-mean.
// One wave = one graph (wave-synchronous, no __syncthreads). 4 graphs/block.
// R4: x is never staged in LDS — layer-1 A-fragments load straight from global
// (two float4 + cvt per k-step; wave touches 16 rows x 128 B contiguous per
// step, coalesced, x read exactly once). LDS holds only act1/act2/adj/colmean,
// all RAW-only (no aliasing, no WAR hazards — the R3 alias of sa1 over sx put
// a ds_write-after-ds_read hazard inside one unrolled window and diverged
// under timing). 28800 B LDS/block.
// Transposed-mix chain: MFMA(A=P, B=adjF) = (adj@P)^T, lane's 4 C-regs =
// 4 consecutive features of node lane&15 -> single b64 LDS write per tile.

typedef _Float16 half4_t __attribute__((ext_vector_type(4)));
typedef _Float16 half8_t __attribute__((ext_vector_type(8)));
typedef float    float4_t __attribute__((ext_vector_type(4)));

// ---------------- prologue: pack W1,W2,W3 (fp32 [K][N]) into fp16 B-frags ----
// frag[(nt*KSTEPS+ks)*64+lane][j] = W[ks*32 + (lane>>4)*8 + j][nt*16 + (lane&15)]
__global__ __launch_bounds__(256) void pack_weights(
    const float* __restrict__ W1, const float* __restrict__ W2,
    const float* __restrict__ W3, _Float16* __restrict__ wf)
{
    const int idx = blockIdx.x * 256 + threadIdx.x;
    if (idx < 4096) {                 // W1: 8 N-tiles x 8 K-steps
        const int lane = idx & 63, ks = (idx >> 6) & 7, nt = idx >> 9;
        const int k0 = ks * 32 + ((lane >> 4) << 3), n = nt * 16 + (lane & 15);
        half8_t h;
        #pragma unroll
        for (int j = 0; j < 8; ++j) h[j] = (_Float16)W1[(k0 + j) * 128 + n];
        *(half8_t*)(wf + (size_t)idx * 8) = h;
    } else if (idx < 5120) {          // W2: 4 x 4
        const int i = idx - 4096;
        const int lane = i & 63, ks = (i >> 6) & 3, nt = i >> 8;
        const int k0 = ks * 32 + ((lane >> 4) << 3), n = nt * 16 + (lane & 15);
        half8_t h;
        #pragma unroll
        for (int j = 0; j < 8; ++j) h[j] = (_Float16)W2[(k0 + j) * 64 + n];
        *(half8_t*)(wf + 32768 + (size_t)i * 8) = h;
    } else if (idx < 5376) {          // W3: 2 x 2
        const int i = idx - 5120;
        const int lane = i & 63, ks = (i >> 6) & 1, nt = i >> 7;
        const int k0 = ks * 32 + ((lane >> 4) << 3), n = nt * 16 + (lane & 15);
        half8_t h;
        #pragma unroll
        for (int j = 0; j < 8; ++j) h[j] = (_Float16)W3[(k0 + j) * 32 + n];
        *(half8_t*)(wf + 40960 + (size_t)i * 8) = h;
    }
}

// ---------------- main kernel ----------------
__global__ __launch_bounds__(256, 4) void gcn_mfma(
    const float* __restrict__ x,    // [B,16,256]
    const float* __restrict__ adj,  // [B,16,16]
    const float* __restrict__ b1, const float* __restrict__ b2,
    const float* __restrict__ b3,
    const _Float16* __restrict__ wf,
    float* __restrict__ out)        // [B,32]
{
    constexpr int A1W = 136;  // act1 row stride: 128+8 halves (16B-aligned rows)
    constexpr int A2W = 72;   // act2 row stride: 64+8
    constexpr int PW = 16 * A1W + 16 * A2W + 256 + 16;  // 3600 halves (7200 B)
    __shared__ _Float16 smem[4 * PW];                   // 28800 B

    const int t = threadIdx.x;
    const int lane = t & 63;
    const int w = t >> 6;
    const int g = blockIdx.x * 4 + w;
    const int q = lane >> 4, n16 = lane & 15;

    _Float16* sa1  = smem + w * PW;          // [0, 2176)
    _Float16* sa2  = sa1 + 16 * A1W;         // [2176, 3328)
    _Float16* sadj = sa1 + 16 * A1W + 16 * A2W;  // [3328, 3584)
    _Float16* sc   = sadj + 256;             // [3584, 3600)

    // ---- stage adj (fp16) + column means c[m] = mean_n adj[n][m]
    {
        const float* ag = adj + (size_t)g * 256;
        float4_t v = *(const float4_t*)(ag + lane * 4);  // n=lane>>2, m=(lane&3)*4..+3
        half4_t h;
        h[0] = (_Float16)v[0]; h[1] = (_Float16)v[1];
        h[2] = (_Float16)v[2]; h[3] = (_Float16)v[3];
        *(half4_t*)(sadj + (lane >> 2) * 16 + (lane & 3) * 4) = h;
        float4_t s = v;
        #pragma unroll
        for (int d = 4; d < 64; d <<= 1) {
            s[0] += __shfl_xor(s[0], d);
            s[1] += __shfl_xor(s[1], d);
            s[2] += __shfl_xor(s[2], d);
            s[3] += __shfl_xor(s[3], d);
        }
        if (lane < 4) {
            half4_t hc;
            hc[0] = (_Float16)(s[0] * 0.0625f); hc[1] = (_Float16)(s[1] * 0.0625f);
            hc[2] = (_Float16)(s[2] * 0.0625f); hc[3] = (_Float16)(s[3] * 0.0625f);
            *(half4_t*)(sc + lane * 4) = hc;
        }
    }

    // adj fragment: value[j] = adj[n16][q*4+j].
    //   as B-operand (16x16x16): B[k=q*4+j][n=n16] = adj^T[k][n]  (mix^T chain)
    const half4_t adjF = *(const half4_t*)(sadj + n16 * 16 + q * 4);
    const float4_t zero = {0.f, 0.f, 0.f, 0.f};

    // ---- layer 1: support1 = x @ W1   (8 N-tiles, 8 K-steps)
    // A-frag straight from global: A[m=n16][k=ks*32+q*8+j] = x[n16][ks*32+q*8+j]
    float4_t acc1[8];
    #pragma unroll
    for (int nt = 0; nt < 8; ++nt) acc1[nt] = zero;
    {
        const float* xr = x + (size_t)g * 4096 + n16 * 256 + q * 8;
        #pragma unroll
        for (int ks = 0; ks < 8; ++ks) {
            float4_t v0 = *(const float4_t*)(xr + ks * 32);
            float4_t v1 = *(const float4_t*)(xr + ks * 32 + 4);
            half8_t a;
            a[0] = (_Float16)v0[0]; a[1] = (_Float16)v0[1];
            a[2] = (_Float16)v0[2]; a[3] = (_Float16)v0[3];
            a[4] = (_Float16)v1[0]; a[5] = (_Float16)v1[1];
            a[6] = (_Float16)v1[2]; a[7] = (_Float16)v1[3];
            #pragma unroll
            for (int nt = 0; nt < 8; ++nt) {
                half8_t b = *(const half8_t*)(wf + ((size_t)(nt * 8 + ks) * 64 + lane) * 8);
                acc1[nt] = __builtin_amdgcn_mfma_f32_16x16x32_f16(a, b, acc1[nt], 0, 0, 0);
            }
        }
    }
    // ---- mix1^T: D = P^T @ adj^T = (adj@P)^T; D[f=q*4+r][n=n16]
    // lane's 4 regs = 4 consecutive features of node n16 -> one b64 write.
    #pragma unroll
    for (int nt = 0; nt < 8; ++nt) {
        half4_t p;
        p[0] = (_Float16)acc1[nt][0]; p[1] = (_Float16)acc1[nt][1];
        p[2] = (_Float16)acc1[nt][2]; p[3] = (_Float16)acc1[nt][3];
        float4_t m = __builtin_amdgcn_mfma_f32_16x16x16f16(p, adjF, zero, 0, 0, 0);
        float4_t bias = *(const float4_t*)(b1 + nt * 16 + q * 4);
        half4_t hm;
        #pragma unroll
        for (int r = 0; r < 4; ++r) hm[r] = (_Float16)fmaxf(m[r] + bias[r], 0.f);
        *(half4_t*)(sa1 + n16 * A1W + nt * 16 + q * 4) = hm;
    }

    // ---- layer 2: support2 = act1 @ W2   (4 N-tiles, 4 K-steps; RAW on sa1)
    float4_t acc2[4];
    #pragma unroll
    for (int nt = 0; nt < 4; ++nt) acc2[nt] = zero;
    for (int ks = 0; ks < 4; ++ks) {
        half8_t a = *(const half8_t*)(sa1 + n16 * A1W + ks * 32 + q * 8);
        #pragma unroll
        for (int nt = 0; nt < 4; ++nt) {
            half8_t b = *(const half8_t*)(wf + 32768 + ((size_t)(nt * 4 + ks) * 64 + lane) * 8);
            acc2[nt] = __builtin_amdgcn_mfma_f32_16x16x32_f16(a, b, acc2[nt], 0, 0, 0);
        }
    }
    // ---- mix2^T + bias + relu -> sa2 (separate region, RAW-only)
    #pragma unroll
    for (int nt = 0; nt < 4; ++nt) {
        half4_t p;
        p[0] = (_Float16)acc2[nt][0]; p[1] = (_Float16)acc2[nt][1];
        p[2] = (_Float16)acc2[nt][2]; p[3] = (_Float16)acc2[nt][3];
        float4_t m = __builtin_amdgcn_mfma_f32_16x16x16f16(p, adjF, zero, 0, 0, 0);
        float4_t bias = *(const float4_t*)(b2 + nt * 16 + q * 4);
        half4_t hm;
        #pragma unroll
        for (int r = 0; r < 4; ++r) hm[r] = (_Float16)fmaxf(m[r] + bias[r], 0.f);
        *(half4_t*)(sa2 + n16 * A2W + nt * 16 + q * 4) = hm;
    }

    // ---- layer 3: support3 = act2 @ W3   (2 N-tiles, 2 K-steps; RAW on sa2)
    float4_t acc3[2];
    acc3[0] = zero; acc3[1] = zero;
    for (int ks = 0; ks < 2; ++ks) {
        half8_t a = *(const half8_t*)(sa2 + n16 * A2W + ks * 32 + q * 8);
        #pragma unroll
        for (int nt = 0; nt < 2; ++nt) {
            half8_t b = *(const half8_t*)(wf + 40960 + ((size_t)(nt * 2 + ks) * 64 + lane) * 8);
            acc3[nt] = __builtin_amdgcn_mfma_f32_16x16x32_f16(a, b, acc3[nt], 0, 0, 0);
        }
    }
    // ---- final: out[f] = colmean(adj)^T @ support3 + b3 (all rows identical)
    const half4_t cf = *(const half4_t*)(sc + q * 4);  // A[m][k]=c[k] broadcast
    #pragma unroll
    for (int nt = 0; nt < 2; ++nt) {
        half4_t p;
        p[0] = (_Float16)acc3[nt][0]; p[1] = (_Float16)acc3[nt][1];
        p[2] = (_Float16)acc3[nt][2]; p[3] = (_Float16)acc3[nt][3];
        float4_t o = __builtin_amdgcn_mfma_f32_16x16x16f16(cf, p, zero, 0, 0, 0);
        if (q == 0)
            out[(size_t)g * 32 + nt * 16 + n16] = o[0] + b3[nt * 16 + n16];
    }
}

extern "C" void kernel_launch(void* const* d_in, const int* in_sizes, int n_in,
                              void* d_out, int out_size, void* d_ws, size_t ws_size,
                              hipStream_t stream) {
    const float* x   = (const float*)d_in[0];
    const float* adj = (const float*)d_in[1];
    const float* W1  = (const float*)d_in[2];
    const float* b1  = (const float*)d_in[3];
    const float* W2  = (const float*)d_in[4];
    const float* b2  = (const float*)d_in[5];
    const float* W3  = (const float*)d_in[6];
    const float* b3  = (const float*)d_in[7];
    _Float16* wf = (_Float16*)d_ws;   // 86016 B of workspace
    pack_weights<<<21, 256, 0, stream>>>(W1, W2, W3, wf);
    gcn_mfma<<<4096, 256, 0, stream>>>(x, adj, b1, b2, b3, wf, (float*)d_out);
}